// Round 1
// baseline (87.441 us; speedup 1.0000x reference)
//
#include <hip/hip_runtime.h>
#include <hip/hip_bf16.h>
#include <stdint.h>

#define N_ROWS 8192
#define M_ROWS 16384
#define CDIM 128

typedef unsigned short u16;
typedef __attribute__((ext_vector_type(2))) unsigned short u16x2;
typedef __attribute__((ext_vector_type(8))) short bf16x8;
typedef __attribute__((ext_vector_type(4))) float f32x4;

static __device__ __forceinline__ u16 f2bf(float x) {
  union { float f; uint32_t u; } v; v.f = x;
  uint32_t u = v.u;
  uint32_t r = u + 0x7FFFu + ((u >> 16) & 1u);  // RTNE (inputs are finite gaussians)
  return (u16)(r >> 16);
}
static __device__ __forceinline__ float bf2f(u16 b) {
  union { uint32_t u; float f; } v; v.u = ((uint32_t)b) << 16;
  return v.f;
}

// One wave per row (24576 rows total). Converts fp32 -> bf16 copies in ws,
// computes row sum-of-squares of the bf16-rounded values (fp32 accumulation),
// and initializes the min-d2 buffer.
__global__ __launch_bounds__(256) void prep_kernel(
    const float* __restrict__ f, const float* __restrict__ m,
    u16* __restrict__ fb, u16* __restrict__ mb,
    float* __restrict__ f2, float* __restrict__ m2, int* __restrict__ mind2)
{
  const int row = blockIdx.x * 4 + (threadIdx.x >> 6);
  const int lane = threadIdx.x & 63;
  const bool isF = row < N_ROWS;
  const float* src = isF ? (f + (size_t)row * CDIM)
                         : (m + (size_t)(row - N_ROWS) * CDIM);
  float2 v = *(const float2*)(src + lane * 2);
  u16 b0 = f2bf(v.x), b1 = f2bf(v.y);
  float x0 = bf2f(b0), x1 = bf2f(b1);
  float s = x0 * x0 + x1 * x1;
#pragma unroll
  for (int mask = 1; mask < 64; mask <<= 1)
    s += __shfl_xor(s, mask, 64);
  u16x2 bb = {b0, b1};
  if (isF) {
    *(u16x2*)(fb + (size_t)row * CDIM + lane * 2) = bb;
    if (lane == 0) { f2[row] = s; mind2[row] = 0x7F7FFFFF; }  // +FLT_MAX bits
  } else {
    const int r = row - N_ROWS;
    *(u16x2*)(mb + (size_t)r * CDIM + lane * 2) = bb;
    if (lane == 0) m2[r] = s;
  }
}

// 128x128 output tile, 4 waves (2x2 of 64x64), full K=128 in LDS.
// grid = (N/128, 8); each block loops over 16 B-tiles (2048 memory rows).
__global__ __launch_bounds__(256, 2) void gemm_min_kernel(
    const u16* __restrict__ fb, const u16* __restrict__ mb,
    const float* __restrict__ f2, const float* __restrict__ m2,
    int* __restrict__ mind2)
{
  __shared__ u16 smA[128 * 128];
  __shared__ u16 smB[128 * 128];
  const int tid = threadIdx.x;
  const int nbase = blockIdx.x * 128;
  const int msplit = blockIdx.y;

  // Stage A once: the tile spans full K, so it is one contiguous 32 KB chunk.
  {
    const u16* srcA = fb + (size_t)nbase * CDIM;
#pragma unroll
    for (int r = 0; r < 8; ++r) {
      const int off = (r * 256 + tid) * 8;  // 16 B per lane, lane-linear LDS
      __builtin_amdgcn_global_load_lds(
          (const __attribute__((address_space(1))) uint32_t*)(srcA + off),
          (__attribute__((address_space(3))) uint32_t*)(&smA[off]), 16, 0, 0);
    }
  }

  const int lane = tid & 63;
  const int w = tid >> 6;
  const int wr = w >> 1, wc = w & 1;
  const int l15 = lane & 15, l4 = lane >> 4;

  float tmin[4][4];
#pragma unroll
  for (int mi = 0; mi < 4; ++mi)
#pragma unroll
    for (int j = 0; j < 4; ++j) tmin[mi][j] = 3.0e38f;

  const int arow0 = wr * 64 + l15;  // + mi*16
  const int brow0 = wc * 64 + l15;  // + ni*16
  const int koff = l4 * 8;          // + ks*32

  for (int it = 0; it < 16; ++it) {
    const int mbase = (msplit * 16 + it) * 128;
    const u16* srcB = mb + (size_t)mbase * CDIM;
#pragma unroll
    for (int r = 0; r < 8; ++r) {
      const int off = (r * 256 + tid) * 8;
      __builtin_amdgcn_global_load_lds(
          (const __attribute__((address_space(1))) uint32_t*)(srcB + off),
          (__attribute__((address_space(3))) uint32_t*)(&smB[off]), 16, 0, 0);
    }
    asm volatile("s_waitcnt vmcnt(0)" ::: "memory");
    __syncthreads();

    f32x4 acc[4][4];
#pragma unroll
    for (int mi = 0; mi < 4; ++mi)
#pragma unroll
      for (int ni = 0; ni < 4; ++ni) acc[mi][ni] = (f32x4){0.f, 0.f, 0.f, 0.f};

#pragma unroll
    for (int ks = 0; ks < 4; ++ks) {
      bf16x8 af[4], bg[4];
#pragma unroll
      for (int mi = 0; mi < 4; ++mi)
        af[mi] = *(const bf16x8*)&smA[(arow0 + mi * 16) * 128 + ks * 32 + koff];
#pragma unroll
      for (int ni = 0; ni < 4; ++ni)
        bg[ni] = *(const bf16x8*)&smB[(brow0 + ni * 16) * 128 + ks * 32 + koff];
#pragma unroll
      for (int mi = 0; mi < 4; ++mi)
#pragma unroll
        for (int ni = 0; ni < 4; ++ni)
          acc[mi][ni] = __builtin_amdgcn_mfma_f32_16x16x32_bf16(
              af[mi], bg[ni], acc[mi][ni], 0, 0, 0);
    }

    // Fused epilogue: t = m2 - 2*cross; keep running row-min in registers.
    // acc[mi][ni][j] -> row (wr*64 + mi*16 + l4*4 + j), col (wc*64 + ni*16 + l15)
#pragma unroll
    for (int ni = 0; ni < 4; ++ni) {
      const float m2v = m2[mbase + wc * 64 + ni * 16 + l15];
#pragma unroll
      for (int mi = 0; mi < 4; ++mi)
#pragma unroll
        for (int j = 0; j < 4; ++j)
          tmin[mi][j] = fminf(tmin[mi][j], fmaf(-2.0f, acc[mi][ni][j], m2v));
    }
    __syncthreads();  // before next iteration overwrites smB
  }

  // Min across the 16 lanes (l15) holding a row's columns.
#pragma unroll
  for (int mi = 0; mi < 4; ++mi)
#pragma unroll
    for (int j = 0; j < 4; ++j) {
      float t = tmin[mi][j];
      t = fminf(t, __shfl_xor(t, 1, 64));
      t = fminf(t, __shfl_xor(t, 2, 64));
      t = fminf(t, __shfl_xor(t, 4, 64));
      t = fminf(t, __shfl_xor(t, 8, 64));
      tmin[mi][j] = t;
    }
  if (l15 == 0) {
#pragma unroll
    for (int mi = 0; mi < 4; ++mi)
#pragma unroll
      for (int j = 0; j < 4; ++j) {
        const int row = nbase + wr * 64 + mi * 16 + l4 * 4 + j;
        const float d2 = fmaxf(f2[row] + tmin[mi][j], 0.0f);  // >= 0 -> int-ordered
        atomicMin(&mind2[row], __float_as_int(d2));
      }
  }
}

__global__ __launch_bounds__(256) void finalize_kernel(
    const int* __restrict__ mind2, float* __restrict__ out)
{
  const int i = blockIdx.x * 256 + threadIdx.x;
  out[i] = sqrtf(fmaxf(__int_as_float(mind2[i]), 0.0f));
}

extern "C" void kernel_launch(void* const* d_in, const int* in_sizes, int n_in,
                              void* d_out, int out_size, void* d_ws, size_t ws_size,
                              hipStream_t stream) {
  const float* f = (const float*)d_in[0];  // features  [8192,1,1,128] fp32
  const float* m = (const float*)d_in[1];  // patch_mem [1,16384,1,128] fp32

  char* ws = (char*)d_ws;
  u16*  fb    = (u16*)(ws);                                   // 2 MB
  u16*  mb    = (u16*)(ws + (2u << 20));                      // 4 MB
  float* f2   = (float*)(ws + (2u << 20) + (4u << 20));       // 32 KB
  float* m2   = (float*)(ws + (2u << 20) + (4u << 20) + (32u << 10));  // 64 KB
  int*  mind2 = (int*)(ws + (2u << 20) + (4u << 20) + (96u << 10));    // 32 KB

  hipLaunchKernelGGL(prep_kernel, dim3((N_ROWS + M_ROWS) / 4), dim3(256), 0, stream,
                     f, m, fb, mb, f2, m2, mind2);
  hipLaunchKernelGGL(gemm_min_kernel, dim3(N_ROWS / 128, 8), dim3(256), 0, stream,
                     fb, mb, f2, m2, mind2);
  hipLaunchKernelGGL(finalize_kernel, dim3(N_ROWS / 256), dim3(256), 0, stream,
                     mind2, (float*)d_out);
}

// Round 2
// 48.550 us; speedup vs baseline: 1.8010x; 1.8010x over previous
//
#include <hip/hip_runtime.h>
#include <hip/hip_bf16.h>
#include <stdint.h>

#define N_ROWS 8192
#define M_ROWS 16384
#define CDIM 128
#define NT 16  // B tiles per block

typedef unsigned short u16;
typedef __attribute__((ext_vector_type(2))) unsigned short u16x2;
typedef __attribute__((ext_vector_type(8))) short bf16x8;
typedef __attribute__((ext_vector_type(4))) float f32x4;

static __device__ __forceinline__ u16 f2bf(float x) {
  union { float f; uint32_t u; } v; v.f = x;
  uint32_t u = v.u;
  uint32_t r = u + 0x7FFFu + ((u >> 16) & 1u);  // RTNE
  return (u16)(r >> 16);
}
static __device__ __forceinline__ float bf2f(u16 b) {
  union { uint32_t u; float f; } v; v.u = ((uint32_t)b) << 16;
  return v.f;
}

// One wave per row: fp32 -> bf16 copies, row sum-of-squares of the
// bf16-rounded values (fp32 accum), init min-d2 buffer.
__global__ __launch_bounds__(256) void prep_kernel(
    const float* __restrict__ f, const float* __restrict__ m,
    u16* __restrict__ fb, u16* __restrict__ mb,
    float* __restrict__ f2, float* __restrict__ m2, int* __restrict__ mind2)
{
  const int row = blockIdx.x * 4 + (threadIdx.x >> 6);
  const int lane = threadIdx.x & 63;
  const bool isF = row < N_ROWS;
  const float* src = isF ? (f + (size_t)row * CDIM)
                         : (m + (size_t)(row - N_ROWS) * CDIM);
  float2 v = *(const float2*)(src + lane * 2);
  u16 b0 = f2bf(v.x), b1 = f2bf(v.y);
  float x0 = bf2f(b0), x1 = bf2f(b1);
  float s = x0 * x0 + x1 * x1;
#pragma unroll
  for (int mask = 1; mask < 64; mask <<= 1)
    s += __shfl_xor(s, mask, 64);
  u16x2 bb = {b0, b1};
  if (isF) {
    *(u16x2*)(fb + (size_t)row * CDIM + lane * 2) = bb;
    if (lane == 0) { f2[row] = s; mind2[row] = 0x7F7FFFFF; }  // +FLT_MAX bits
  } else {
    const int r = row - N_ROWS;
    *(u16x2*)(mb + (size_t)r * CDIM + lane * 2) = bb;
    if (lane == 0) m2[r] = s;
  }
}

// Stage one 128x128 bf16 tile (32 KB) into LDS, linear dest, with the
// global SOURCE pre-swizzled so that reads can apply byte ^= ((row&7)<<4).
// t16 = 16B-chunk index; src chunk = t16 ^ ((t16>>4)&7)  (XOR involution).
static __device__ __forceinline__ void stage_tile(const u16* __restrict__ src,
                                                  u16* __restrict__ dst, int tid) {
#pragma unroll
  for (int r = 0; r < 8; ++r) {
    const int t16 = r * 256 + tid;
    const int srcOff = (t16 ^ ((t16 >> 4) & 7)) * 8;  // u16 units
    const int dstOff = t16 * 8;
    __builtin_amdgcn_global_load_lds(
        (const __attribute__((address_space(1))) uint32_t*)(src + srcOff),
        (__attribute__((address_space(3))) uint32_t*)(dst + dstOff), 16, 0, 0);
  }
}

// 128x128 output tile, 4 waves (2x2 of 64x64). A held in registers (full
// K=128), B double-buffered in LDS with prefetch-early + counted vmcnt.
// grid = (8 msplit, 64 ntile): consecutive block ids share a B slice -> one
// 512KB B-slice per XCD, L2-resident.
__global__ __launch_bounds__(256, 2) void gemm_min_kernel(
    const u16* __restrict__ fb, const u16* __restrict__ mb,
    const float* __restrict__ f2, const float* __restrict__ m2,
    int* __restrict__ mind2)
{
  __shared__ u16 smB[2][128 * 128];
  const int tid = threadIdx.x;
  const int msplit = blockIdx.x;
  const int nbase = blockIdx.y * 128;

  const int lane = tid & 63;
  const int w = tid >> 6;
  const int wr = w >> 1, wc = w & 1;
  const int l15 = lane & 15, l4 = lane >> 4;
  const int sw = (l15 & 7) << 4;  // read-side XOR (bytes)

  // Prologue: stage A into smB[1], B tile 0 into smB[0].
  stage_tile(fb + (size_t)nbase * CDIM, smB[1], tid);
  stage_tile(mb + (size_t)(msplit * NT) * 128 * CDIM, smB[0], tid);
  asm volatile("s_waitcnt vmcnt(0)" ::: "memory");
  __builtin_amdgcn_s_barrier();

  // A fragments -> registers (64 VGPRs), swizzled read.
  bf16x8 af[4][4];  // [mi][ks]
#pragma unroll
  for (int mi = 0; mi < 4; ++mi)
#pragma unroll
    for (int ks = 0; ks < 4; ++ks) {
      const int row = wr * 64 + mi * 16 + l15;
      const int cb = (ks * 64 + l4 * 16) ^ sw;
      af[mi][ks] = *(const bf16x8*)&smB[1][row * 128 + (cb >> 1)];
    }
  __syncthreads();  // all waves done reading A before smB[1] is reused

  float tmin[4][4];
#pragma unroll
  for (int mi = 0; mi < 4; ++mi)
#pragma unroll
    for (int j = 0; j < 4; ++j) tmin[mi][j] = 3.0e38f;

  int cur = 0;
  for (int it = 0; it < NT; ++it) {
    const int mbase = (msplit * NT + it) * 128;
    if (it + 1 < NT) {
      stage_tile(mb + (size_t)(mbase + 128) * CDIM, smB[cur ^ 1], tid);
      asm volatile("s_waitcnt vmcnt(8)" ::: "memory");  // current tile landed
    } else {
      asm volatile("s_waitcnt vmcnt(0)" ::: "memory");
    }
    __builtin_amdgcn_s_barrier();

    const u16* smcur = smB[cur];
    f32x4 acc[4][4];
#pragma unroll
    for (int mi = 0; mi < 4; ++mi)
#pragma unroll
      for (int ni = 0; ni < 4; ++ni) acc[mi][ni] = (f32x4){0.f, 0.f, 0.f, 0.f};

#pragma unroll
    for (int ks = 0; ks < 4; ++ks) {
      bf16x8 bg[4];
#pragma unroll
      for (int ni = 0; ni < 4; ++ni) {
        const int row = wc * 64 + ni * 16 + l15;
        const int cb = (ks * 64 + l4 * 16) ^ sw;
        bg[ni] = *(const bf16x8*)&smcur[row * 128 + (cb >> 1)];
      }
#pragma unroll
      for (int mi = 0; mi < 4; ++mi)
#pragma unroll
        for (int ni = 0; ni < 4; ++ni)
          acc[mi][ni] = __builtin_amdgcn_mfma_f32_16x16x32_bf16(
              af[mi][ks], bg[ni], acc[mi][ni], 0, 0, 0);
    }

    // Fused epilogue: t = m2 - 2*cross; running row-min in registers.
    // acc[mi][ni][j] -> row (wr*64+mi*16+l4*4+j), col (wc*64+ni*16+l15)
#pragma unroll
    for (int ni = 0; ni < 4; ++ni) {
      const float m2v = m2[mbase + wc * 64 + ni * 16 + l15];
#pragma unroll
      for (int mi = 0; mi < 4; ++mi)
#pragma unroll
        for (int j = 0; j < 4; ++j)
          tmin[mi][j] = fminf(tmin[mi][j], fmaf(-2.0f, acc[mi][ni][j], m2v));
    }
    __syncthreads();  // all reads of smB[cur] done before next overwrite
    cur ^= 1;
  }

  // Min across the 16 lanes (l15) holding a row's columns.
#pragma unroll
  for (int mi = 0; mi < 4; ++mi)
#pragma unroll
    for (int j = 0; j < 4; ++j) {
      float t = tmin[mi][j];
      t = fminf(t, __shfl_xor(t, 1, 64));
      t = fminf(t, __shfl_xor(t, 2, 64));
      t = fminf(t, __shfl_xor(t, 4, 64));
      t = fminf(t, __shfl_xor(t, 8, 64));
      tmin[mi][j] = t;
    }
  if (l15 == 0) {
#pragma unroll
    for (int mi = 0; mi < 4; ++mi)
#pragma unroll
      for (int j = 0; j < 4; ++j) {
        const int row = nbase + wr * 64 + mi * 16 + l4 * 4 + j;
        const float d2 = fmaxf(f2[row] + tmin[mi][j], 0.0f);
        atomicMin(&mind2[row], __float_as_int(d2));
      }
  }
}

__global__ __launch_bounds__(256) void finalize_kernel(
    const int* __restrict__ mind2, float* __restrict__ out)
{
  const int i = blockIdx.x * 256 + threadIdx.x;
  out[i] = sqrtf(fmaxf(__int_as_float(mind2[i]), 0.0f));
}

extern "C" void kernel_launch(void* const* d_in, const int* in_sizes, int n_in,
                              void* d_out, int out_size, void* d_ws, size_t ws_size,
                              hipStream_t stream) {
  const float* f = (const float*)d_in[0];  // features  [8192,1,1,128] fp32
  const float* m = (const float*)d_in[1];  // patch_mem [1,16384,1,128] fp32

  char* ws = (char*)d_ws;
  u16*  fb    = (u16*)(ws);                                   // 2 MB
  u16*  mb    = (u16*)(ws + (2u << 20));                      // 4 MB
  float* f2   = (float*)(ws + (2u << 20) + (4u << 20));       // 32 KB
  float* m2   = (float*)(ws + (2u << 20) + (4u << 20) + (32u << 10));  // 64 KB
  int*  mind2 = (int*)(ws + (2u << 20) + (4u << 20) + (96u << 10));    // 32 KB

  hipLaunchKernelGGL(prep_kernel, dim3((N_ROWS + M_ROWS) / 4), dim3(256), 0, stream,
                     f, m, fb, mb, f2, m2, mind2);
  hipLaunchKernelGGL(gemm_min_kernel, dim3(8, N_ROWS / 128), dim3(256), 0, stream,
                     fb, mb, f2, m2, mind2);
  hipLaunchKernelGGL(finalize_kernel, dim3(N_ROWS / 256), dim3(256), 0, stream,
                     mind2, (float*)d_out);
}